// Round 5
// baseline (128.540 us; speedup 1.0000x reference)
//
#include <hip/hip_runtime.h>

#define NSC 64      // Ns
#define NWN 12      // nw
#define LWN 6       // lw
#define NZD 200     // Nz
#define NSTEPS 40   // (lw-1)*SPD
#define NFRAMES 6
#define NL 4        // cells per lane
#define ACTL 50     // active lanes (50*4 = 200)
#define NCPW 2      // columns per wave

__device__ __forceinline__ float frcp(float x) { return __builtin_amdgcn_rcpf(x); }
__device__ __forceinline__ float frsq(float x) { return __builtin_amdgcn_rsqf(x); }
__device__ __forceinline__ float bperm(int addr, float v) {
    return __int_as_float(__builtin_amdgcn_ds_bpermute(addr, __float_as_int(v)));
}

template<int CTRL, int RMASK, bool BC>
__device__ __forceinline__ float dppadd(float x) {
    const int t = __builtin_amdgcn_update_dpp(0, __float_as_int(x), CTRL, RMASK, 0xf, BC);
    return x + __int_as_float(t);
}
// wave64 inclusive scan, 6 VALU-DPP ops
__device__ __forceinline__ float wave_iscan(float x) {
    x = dppadd<0x111, 0xf, true>(x);
    x = dppadd<0x112, 0xf, true>(x);
    x = dppadd<0x114, 0xf, true>(x);
    x = dppadd<0x118, 0xf, true>(x);
    x = dppadd<0x142, 0xa, false>(x);
    x = dppadd<0x143, 0xc, false>(x);
    return x;
}

__device__ __forceinline__ float weno3z_f(float qm, float q0, float qp) {
    const float qi1 = -0.5f * qm + 1.5f * q0;
    const float qi2 = 0.5f * (q0 + qp);
    const float b1 = (q0 - qm) * (q0 - qm);
    const float b2 = (qp - q0) * (qp - q0);
    const float tau = fabsf(b2 - b1);
    const float w1 = (1.f / 3.f) * (1.f + tau * frcp(b1 + 1e-14f));
    const float w2 = (2.f / 3.f) * (1.f + tau * frcp(b2 + 1e-14f));
    return (w1 * qi1 + w2 * qi2) * frcp(w1 + w2);
}

__global__ __launch_bounds__(64, 1) void nnpzd_wave(
    const float* __restrict__ Kz, const float* __restrict__ I0,
    const float* __restrict__ alpha_p, const float* __restrict__ Xi_p,
    const float* __restrict__ rho_p, const float* __restrict__ gamma_p,
    const float* __restrict__ Gamma_p, const float* __restrict__ varphi_p,
    const float* __restrict__ omega_p, const float* __restrict__ beta_p,
    const float* __restrict__ NO3_0, const float* __restrict__ NH4_0,
    const float* __restrict__ P_0, const float* __restrict__ Z_0,
    const float* __restrict__ D_0, const float* __restrict__ subw,
    const float* __restrict__ zT, const float* __restrict__ zw,
    float* __restrict__ out)
{
    const float XI = 0.067f, ZETA = 0.0095f, LAM = 0.06f, PSI = 1.46f;
    const float MU = 0.25f, ETA = 1.5f, KAP = 1.0f, DT = 0.125f;

    const int col0 = blockIdx.x * NCPW;     // two adjacent windows, same scenario
    const int si   = col0 / NWN;
    const int wi0  = col0 - si * NWN;       // even; wi0+1 < 12 always
    const int lane = threadIdx.x;
    const bool act = lane < ACTL;
    const int  c0  = lane * NL;

    // ---- bpermute byte addresses ----
    const int aM1 = ((lane > 0) ? lane - 1 : 0) * 4;
    const int aP1 = ((lane < 63) ? lane + 1 : 63) * 4;
    int aUp[2], aDn[2];
    #pragma unroll
    for (int r = 0; r < 2; ++r) {
        const int off = 1 << r;
        aUp[r] = ((lane >= off) ? lane - off : 0) * 4;
        aDn[r] = ((lane + off < 64) ? lane + off : 63) * 4;
    }

    // scenario scalars (shared by both columns)
    const float pa   = alpha_p[si];
    const float pXi  = Xi_p[si];
    const float prho = rho_p[si];
    const float pgam = gamma_p[si];
    const float pGam = Gamma_p[si];
    const float pvar = varphi_p[si];
    const float sedc = omega_p[si];
    const float pbet = beta_p[si];
    int sw0[NCPW];
    #pragma unroll
    for (int c = 0; c < NCPW; ++c) sw0[c] = (int)subw[(wi0 + c) * LWN];

    // ---- shared per-lane geometry ----
    float dzT[NL], DTdz[NL], ezT[NL], kAf[NL], kCf[NL], swN[NL], swN4;
    {
        float dzw_[NL + 2];
        #pragma unroll
        for (int j = 0; j <= NL + 1; ++j) {
            const int i = act ? (c0 + j) : 0;
            dzw_[j] = (i == 0)   ? 0.5f * (zw[1] - zw[0])
                    : (i >= NZD) ? 0.5f * (zw[NZD] - zw[NZD - 1])
                                 : (zT[i] - zT[i - 1]);
        }
        #pragma unroll
        for (int j = 0; j < NL; ++j) {
            const int i = act ? (c0 + j) : 0;
            const float dz = zw[i + 1] - zw[i];
            dzT[j]  = dz;
            DTdz[j] = act ? (DT / dz) : 0.f;
            ezT[j]  = expf(-XI * zT[i]);
            kAf[j]  = (act && (c0 + j) >= 1)       ? (-DT / (dz * dzw_[j]))     : 0.f;
            kCf[j]  = (act && (c0 + j) <= NZD - 2) ? (-DT / (dz * dzw_[j + 1])) : 0.f;
            swN[j]  = act ? (sedc / dzw_[j]) : 0.f;
        }
        swN4 = act ? (sedc / dzw_[NL]) : 0.f;
    }

    // ---- state for both columns ----
    float vN[NCPW][NL], vA[NCPW][NL], vP[NCPW][NL], vZ[NCPW][NL], vD[NCPW][NL];
    #pragma unroll
    for (int c = 0; c < NCPW; ++c) {
        const size_t ib = (size_t)(col0 + c) * NZD + c0;
        if (act) {
            const float4 n4 = *reinterpret_cast<const float4*>(&NO3_0[ib]);
            const float4 a4 = *reinterpret_cast<const float4*>(&NH4_0[ib]);
            const float4 p4 = *reinterpret_cast<const float4*>(&P_0[ib]);
            const float4 z4 = *reinterpret_cast<const float4*>(&Z_0[ib]);
            const float4 d4 = *reinterpret_cast<const float4*>(&D_0[ib]);
            vN[c][0]=n4.x; vN[c][1]=n4.y; vN[c][2]=n4.z; vN[c][3]=n4.w;
            vA[c][0]=a4.x; vA[c][1]=a4.y; vA[c][2]=a4.z; vA[c][3]=a4.w;
            vP[c][0]=p4.x; vP[c][1]=p4.y; vP[c][2]=p4.z; vP[c][3]=p4.w;
            vZ[c][0]=z4.x; vZ[c][1]=z4.y; vZ[c][2]=z4.z; vZ[c][3]=z4.w;
            vD[c][0]=d4.x; vD[c][1]=d4.y; vD[c][2]=d4.z; vD[c][3]=d4.w;
        } else {
            #pragma unroll
            for (int j = 0; j < NL; ++j) { vN[c][j]=vA[c][j]=vP[c][j]=vZ[c][j]=vD[c][j]=0.f; }
        }
    }

    // frame 0
    #pragma unroll
    for (int c = 0; c < NCPW; ++c) {
        const size_t ob = (size_t)(col0 + c) * (NFRAMES * 5 * NZD) + c0;
        if (act) {
            *reinterpret_cast<float4*>(&out[ob + 0 * NZD]) = make_float4(vN[c][0],vN[c][1],vN[c][2],vN[c][3]);
            *reinterpret_cast<float4*>(&out[ob + 1 * NZD]) = make_float4(vA[c][0],vA[c][1],vA[c][2],vA[c][3]);
            *reinterpret_cast<float4*>(&out[ob + 2 * NZD]) = make_float4(vP[c][0],vP[c][1],vP[c][2],vP[c][3]);
            *reinterpret_cast<float4*>(&out[ob + 3 * NZD]) = make_float4(vZ[c][0],vZ[c][1],vZ[c][2],vZ[c][3]);
            *reinterpret_cast<float4*>(&out[ob + 4 * NZD]) = make_float4(vD[c][0],vD[c][1],vD[c][2],vD[c][3]);
        }
    }

    const float* KzBase = Kz + (size_t)si * (2 * NWN * LWN + 2) * (NZD + 1);
    const float* I0row  = I0 + (size_t)si * (NWN * LWN + 1);

    // ---- per-column factors (rebuilt every 4 steps) ----
    float t00[NCPW], t10[NCPW], t11[NCPW], t20[NCPW], t21[NCPW], t22[NCPW];
    float t30[NCPW], t31[NCPW], t32[NCPW], t33[NCPW];
    float ecf0[NCPW], ecf1[NCPW], ecf2[NCPW];
    float aa0[NCPW], aa1[NCPW], aa2[NCPW];
    float cl0[NCPW], cl1[NCPW], cl2[NCPW], cl3[NCPW];
    float E1a[NCPW], E2a[NCPW], E1b[NCPW], E2b[NCPW], invbF[NCPW];
    float Iez[NCPW][NL], rap[NCPW];
    float kzc[NCPW][NL + 1];

    #pragma unroll
    for (int c = 0; c < NCPW; ++c) {
        const float* kzp = KzBase + (size_t)(2 * sw0[c]) * (NZD + 1);
        #pragma unroll
        for (int j = 0; j <= NL; ++j) kzc[c][j] = act ? kzp[c0 + j] : 0.f;
        rap[c] = 0.f;
    }

    for (int k = 0; k < NSTEPS; ++k) {
        const int day = k >> 3, hh = k >> 2;

        if ((k & 3) == 0) {
            #pragma unroll
            for (int c = 0; c < NCPW; ++c) {
                float ac_[NL], cc_[NL];
                #pragma unroll
                for (int j = 0; j < NL; ++j) {
                    ac_[j] = kAf[j] * kzc[c][j];
                    cc_[j] = kCf[j] * kzc[c][j + 1];
                }
                {   // prefetch next Kz row for this column
                    const float* kzp = KzBase + (size_t)(2 * sw0[c] + hh + 1) * (NZD + 1);
                    #pragma unroll
                    for (int j = 0; j <= NL; ++j) kzc[c][j] = act ? kzp[c0 + j] : 0.f;
                }
                // Thomas LU factors
                const float iv0 = frcp(1.f - ac_[0] - cc_[0]);
                cl0[c] = cc_[0] * iv0;
                aa0[c] = ac_[0] * iv0;
                t00[c] = iv0;
                const float iv1 = frcp(1.f - ac_[1] - cc_[1] - ac_[1] * cl0[c]);
                const float qf1 = ac_[1] * iv1;
                cl1[c] = cc_[1] * iv1;
                aa1[c] = -qf1 * aa0[c];
                t11[c] = iv1; t10[c] = -qf1 * t00[c];
                const float iv2 = frcp(1.f - ac_[2] - cc_[2] - ac_[2] * cl1[c]);
                const float qf2 = ac_[2] * iv2;
                cl2[c] = cc_[2] * iv2;
                aa2[c] = -qf2 * aa1[c];
                t22[c] = iv2; t21[c] = -qf2 * t11[c]; t20[c] = -qf2 * t10[c];
                const float iv3 = frcp(1.f - ac_[3] - cc_[3] - ac_[3] * cl2[c]);
                const float qf3 = ac_[3] * iv3;
                cl3[c] = cc_[3] * iv3;
                const float aa3 = -qf3 * aa2[c];
                t33[c] = iv3; t32[c] = -qf3 * t22[c]; t31[c] = -qf3 * t21[c]; t30[c] = -qf3 * t20[c];
                // Ec coefficients
                const float c01 = cl0[c] * cl1[c];
                ecf0[c] = t00[c] - cl0[c] * t10[c] + c01 * t20[c];
                ecf1[c] = -cl0[c] * t11[c] + c01 * t21[c];
                ecf2[c] = c01 * t22[c];
                // spike + reduced system
                const float F = aa0[c] - cl0[c] * (aa1[c] - cl1[c] * aa2[c]);
                const float G = cl0[c] * cl1[c] * cl2[c];
                const float Fn = bperm(aP1, F);
                const float Gn = bperm(aP1, G);
                float aR = aa3;
                float bR = 1.f - cl3[c] * Fn;
                float cR = -cl3[c] * Gn;
                if (!act) { aR = 0.f; bR = 1.f; cR = 0.f; }
                // PCR round 1
                const float ib  = frcp(bR);
                const float am  = bperm(aUp[0], aR), ibm = bperm(aUp[0], ib), cm = bperm(aUp[0], cR);
                const float ap  = bperm(aDn[0], aR), ibp = bperm(aDn[0], ib), cp = bperm(aDn[0], cR);
                E1a[c] = -aR * ibm;
                E2a[c] = -cR * ibp;
                const float b1 = bR + E1a[c] * cm + E2a[c] * ap;
                const float a1 = E1a[c] * am;
                const float c1 = E2a[c] * cp;
                // PCR round 2
                const float ib1  = frcp(b1);
                const float am2  = bperm(aUp[1], a1), ib1m = bperm(aUp[1], ib1), cm2 = bperm(aUp[1], c1);
                const float ap2  = bperm(aDn[1], a1), ib1p = bperm(aDn[1], ib1), cp2 = bperm(aDn[1], c1);
                E1b[c] = -a1 * ib1m;
                E2b[c] = -c1 * ib1p;
                const float b2 = b1 + E1b[c] * cm2 + E2b[c] * ap2;
                invbF[c] = frcp(b2);
            }
        }
        if ((k & 7) == 0) {
            #pragma unroll
            for (int c = 0; c < NCPW; ++c) {
                const float I0d = I0row[sw0[c] + day];
                #pragma unroll
                for (int j = 0; j < NL; ++j) Iez[c][j] = I0d * ezT[j];
                const float sw = subw[(wi0 + c) * LWN + day + 1];
                rap[c] = 0.05f * (fminf(fmaxf(sw - 30.f, 0.f), 1.f)
                                - fminf(fmaxf(sw - 60.f, 0.f), 1.f));
            }
        }

        // ---- bio tendencies + RHS, both columns ----
        float dd[NCPW][5][NL];
        #pragma unroll
        for (int c = 0; c < NCPW; ++c) {
            float cl_[NL];
            float run = 0.f;
            #pragma unroll
            for (int j = 0; j < NL; ++j) { run += vP[c][j] * dzT[j]; cl_[j] = run; }
            const float pref = wave_iscan(run) - run;
            #pragma unroll
            for (int j = 0; j < NL; ++j) {
                const float csum = pref + cl_[j];
                const float It   = Iez[c][j] * __expf(-ZETA * csum);
                const float aIt  = pa * It;
                const float Gg   = ETA * aIt * frsq(ETA * ETA + aIt * aIt);
                const float fN   = vN[c][j] * frcp(KAP + vN[c][j]);
                const float fA   = vA[c][j] * frcp(KAP + vA[c][j]);
                const float eP   = __expf(-PSI * vA[c][j]);
                const float graz = prho * (1.f - __expf(-LAM * vP[c][j])) * vZ[c][j];
                const float bN = MU * vA[c][j] - Gg * eP * vP[c][j] * fN;
                const float bA = pvar * vD[c][j] + pGam * vZ[c][j] - Gg * vP[c][j] * fA - MU * vA[c][j];
                const float bP = Gg * vP[c][j] * (eP * fN + fA) - graz - pXi * vP[c][j];
                const float bZ = (1.f - pgam) * graz - pGam * vZ[c][j];
                const float bD = pgam * graz + pXi * vP[c][j] - pvar * vD[c][j];
                dd[c][0][j] = vN[c][j] + DT * bN;
                dd[c][1][j] = vA[c][j] + DT * bA;
                dd[c][2][j] = vP[c][j] + DT * bP;
                dd[c][3][j] = vZ[c][j] + DT * bZ;
                dd[c][4][j] = vD[c][j] + DT * bD;
            }
        }

        // ---- solve all tracers, both columns (10 independent chains) ----
        float xD[NCPW][NL];
        #pragma unroll
        for (int c = 0; c < NCPW; ++c) {
            #pragma unroll
            for (int t = 0; t < 5; ++t) {
                const float Ec = ecf0[c] * dd[c][t][0] + ecf1[c] * dd[c][t][1] + ecf2[c] * dd[c][t][2];
                const float En = bperm(aP1, Ec);
                const float Dt3 = t30[c] * dd[c][t][0] + t31[c] * dd[c][t][1]
                                + t32[c] * dd[c][t][2] + t33[c] * dd[c][t][3];
                float dR = Dt3 - cl3[c] * En;
                {
                    const float dm = bperm(aUp[0], dR);
                    const float dp = bperm(aDn[0], dR);
                    dR += E1a[c] * dm + E2a[c] * dp;
                }
                {
                    const float dm = bperm(aUp[1], dR);
                    const float dp = bperm(aDn[1], dR);
                    dR += E1b[c] * dm + E2b[c] * dp;
                }
                const float y  = dR * invbF[c];
                const float xm = bperm(aM1, y);
                const float Dt0 = t00[c] * dd[c][t][0];
                const float Dt1 = t10[c] * dd[c][t][0] + t11[c] * dd[c][t][1];
                const float Dt2 = t20[c] * dd[c][t][0] + t21[c] * dd[c][t][1] + t22[c] * dd[c][t][2];
                const float X3 = y;
                const float X2 = Dt2 - aa2[c] * xm - cl2[c] * X3;
                const float X1 = Dt1 - aa1[c] * xm - cl1[c] * X2;
                const float X0 = Dt0 - aa0[c] * xm - cl0[c] * X1;
                if (t == 0) {
                    vN[c][0] = X0 + (pbet - X0) * rap[c];
                    vN[c][1] = X1 + (pbet - X1) * rap[c];
                    vN[c][2] = X2 + (pbet - X2) * rap[c];
                    vN[c][3] = X3 + (pbet - X3) * rap[c];
                } else if (t == 1) {
                    vA[c][0] = X0; vA[c][1] = X1; vA[c][2] = X2; vA[c][3] = X3;
                } else if (t == 2) {
                    vP[c][0] = X0; vP[c][1] = X1; vP[c][2] = X2; vP[c][3] = X3;
                } else if (t == 3) {
                    vZ[c][0] = X0; vZ[c][1] = X1; vZ[c][2] = X2; vZ[c][3] = X3;
                } else {
                    xD[c][0] = X0; xD[c][1] = X1; xD[c][2] = X2; xD[c][3] = X3;
                }
            }
        }

        // ---- WENO3-Z sediment flux + D commit, both columns ----
        #pragma unroll
        for (int c = 0; c < NCPW; ++c) {
            float q[NL];
            #pragma unroll
            for (int j = 0; j < NL; ++j) q[j] = xD[c][j] * dzT[j];
            const float qm2 = bperm(aM1, q[2]);
            const float qm1 = bperm(aM1, q[3]);
            const float qn0 = bperm(aP1, q[0]);
            const float f0 = (lane == 0) ? 0.f              : weno3z_f(qm2, qm1, q[0]) * swN[0];
            const float f1 = (lane == 0) ? sedc * xD[c][0]  : weno3z_f(qm1, q[0], q[1]) * swN[1];
            const float f2 = weno3z_f(q[0], q[1], q[2]) * swN[2];
            const float f3 = weno3z_f(q[1], q[2], q[3]) * swN[3];
            const float f4 = (lane == ACTL - 1) ? sedc * xD[c][3]
                                                : weno3z_f(q[2], q[3], qn0) * swN4;
            const float fs[NL + 1] = { f0, f1, f2, f3, f4 };
            #pragma unroll
            for (int j = 0; j < NL; ++j)
                vD[c][j] = xD[c][j] + (fs[j] - fs[j + 1]) * DTdz[j];
        }

        if (((k + 1) & 7) == 0 && act) {
            const int fr = (k + 1) >> 3;
            #pragma unroll
            for (int c = 0; c < NCPW; ++c) {
                const size_t ob = (size_t)(col0 + c) * (NFRAMES * 5 * NZD)
                                + (size_t)fr * (5 * NZD) + c0;
                *reinterpret_cast<float4*>(&out[ob + 0 * NZD]) = make_float4(vN[c][0],vN[c][1],vN[c][2],vN[c][3]);
                *reinterpret_cast<float4*>(&out[ob + 1 * NZD]) = make_float4(vA[c][0],vA[c][1],vA[c][2],vA[c][3]);
                *reinterpret_cast<float4*>(&out[ob + 2 * NZD]) = make_float4(vP[c][0],vP[c][1],vP[c][2],vP[c][3]);
                *reinterpret_cast<float4*>(&out[ob + 3 * NZD]) = make_float4(vZ[c][0],vZ[c][1],vZ[c][2],vZ[c][3]);
                *reinterpret_cast<float4*>(&out[ob + 4 * NZD]) = make_float4(vD[c][0],vD[c][1],vD[c][2],vD[c][3]);
            }
        }
    }
}

extern "C" void kernel_launch(void* const* d_in, const int* in_sizes, int n_in,
                              void* d_out, int out_size, void* d_ws, size_t ws_size,
                              hipStream_t stream) {
    const float* Kz    = (const float*)d_in[0];
    const float* I0    = (const float*)d_in[1];
    const float* alpha = (const float*)d_in[2];
    const float* Xi    = (const float*)d_in[3];
    const float* rho   = (const float*)d_in[4];
    const float* gam   = (const float*)d_in[5];
    const float* Gam   = (const float*)d_in[6];
    const float* varp  = (const float*)d_in[7];
    const float* omg   = (const float*)d_in[8];
    const float* bet   = (const float*)d_in[9];
    const float* N0    = (const float*)d_in[10];
    const float* A0    = (const float*)d_in[11];
    const float* P0    = (const float*)d_in[12];
    const float* Z0    = (const float*)d_in[13];
    const float* Dd0   = (const float*)d_in[14];
    const float* sbw   = (const float*)d_in[15];
    const float* zTp   = (const float*)d_in[16];
    const float* zwp   = (const float*)d_in[17];
    float* out = (float*)d_out;

    dim3 grid(NSC * NWN / NCPW);   // 384 waves, 2 columns each
    dim3 block(64);
    hipLaunchKernelGGL(nnpzd_wave, grid, block, 0, stream,
                       Kz, I0, alpha, Xi, rho, gam, Gam, varp, omg, bet,
                       N0, A0, P0, Z0, Dd0, sbw, zTp, zwp, out);
}

// Round 7
// 57.101 us; speedup vs baseline: 2.2511x; 2.2511x over previous
//
#include <hip/hip_runtime.h>

#define NSC 64      // Ns
#define NWN 12      // nw
#define LWN 6       // lw
#define NZD 200     // Nz
#define NSTEPS 40   // (lw-1)*SPD
#define NFRAMES 6
#define NL 4        // cells per lane
#define ACTL 50     // active lanes (50*4 = 200)

__device__ __forceinline__ float frcp(float x) { return __builtin_amdgcn_rcpf(x); }
__device__ __forceinline__ float frsq(float x) { return __builtin_amdgcn_rsqf(x); }

// DPP lane-shift moves (gfx9-family wave shifts; bound_ctrl -> 0 at edges).
// wave_shr1 (0x138): lane i reads lane i-1  (same direction family as row_shr used in scans)
// wave_shl1 (0x130): lane i reads lane i+1
template<int CTRL>
__device__ __forceinline__ float dppmov(float x) {
    return __int_as_float(__builtin_amdgcn_update_dpp(0, __float_as_int(x), CTRL, 0xf, 0xf, true));
}
__device__ __forceinline__ float nbr_p1(float x) { return dppmov<0x130>(x); }  // from lane+1 (wave_shl1)
__device__ __forceinline__ float nbr_m1(float x) { return dppmov<0x138>(x); }  // from lane-1 (wave_shr1)
__device__ __forceinline__ float nbr_p2(float x) { return nbr_p1(nbr_p1(x)); }
__device__ __forceinline__ float nbr_m2(float x) { return nbr_m1(nbr_m1(x)); }

template<int CTRL, int RMASK, bool BC>
__device__ __forceinline__ float dppadd(float x) {
    const int t = __builtin_amdgcn_update_dpp(0, __float_as_int(x), CTRL, RMASK, 0xf, BC);
    return x + __int_as_float(t);
}
// wave64 inclusive scan, 6 VALU-DPP ops
__device__ __forceinline__ float wave_iscan(float x) {
    x = dppadd<0x111, 0xf, true>(x);
    x = dppadd<0x112, 0xf, true>(x);
    x = dppadd<0x114, 0xf, true>(x);
    x = dppadd<0x118, 0xf, true>(x);
    x = dppadd<0x142, 0xa, false>(x);
    x = dppadd<0x143, 0xc, false>(x);
    return x;
}

__device__ __forceinline__ float weno3z_f(float qm, float q0, float qp) {
    const float qi1 = -0.5f * qm + 1.5f * q0;
    const float qi2 = 0.5f * (q0 + qp);
    const float b1 = (q0 - qm) * (q0 - qm);
    const float b2 = (qp - q0) * (qp - q0);
    const float tau = fabsf(b2 - b1);
    const float w1 = (1.f / 3.f) * (1.f + tau * frcp(b1 + 1e-14f));
    const float w2 = (2.f / 3.f) * (1.f + tau * frcp(b2 + 1e-14f));
    return (w1 * qi1 + w2 * qi2) * frcp(w1 + w2);
}

__global__ __launch_bounds__(64) void nnpzd_wave(
    const float* __restrict__ Kz, const float* __restrict__ I0,
    const float* __restrict__ alpha_p, const float* __restrict__ Xi_p,
    const float* __restrict__ rho_p, const float* __restrict__ gamma_p,
    const float* __restrict__ Gamma_p, const float* __restrict__ varphi_p,
    const float* __restrict__ omega_p, const float* __restrict__ beta_p,
    const float* __restrict__ NO3_0, const float* __restrict__ NH4_0,
    const float* __restrict__ P_0, const float* __restrict__ Z_0,
    const float* __restrict__ D_0, const float* __restrict__ subw,
    const float* __restrict__ zT, const float* __restrict__ zw,
    float* __restrict__ out)
{
    const float XI = 0.067f, ZETA = 0.0095f, LAM = 0.06f, PSI = 1.46f;
    const float MU = 0.25f, ETA = 1.5f, KAP = 1.0f, DT = 0.125f;

    const int col  = blockIdx.x;            // one column per wave
    const int si   = col / NWN;
    const int wi   = col - si * NWN;
    const int lane = threadIdx.x;           // blockDim = 64 = one wave
    const bool act = lane < ACTL;
    const int  c0  = lane * NL;

    const float pa   = alpha_p[si];
    const float pXi  = Xi_p[si];
    const float prho = rho_p[si];
    const float pgam = gamma_p[si];
    const float pGam = Gamma_p[si];
    const float pvar = varphi_p[si];
    const float sedc = omega_p[si];
    const float pbet = beta_p[si];
    const int   sw0  = (int)subw[wi * LWN];

    // ---- per-lane constant geometry ----
    float dzT[NL], DTdz[NL], ezT[NL], kAf[NL], kCf[NL], swN[NL], swN4;
    {
        float dzw_[NL + 2];
        #pragma unroll
        for (int j = 0; j <= NL + 1; ++j) {
            const int i = act ? (c0 + j) : 0;
            dzw_[j] = (i == 0)   ? 0.5f * (zw[1] - zw[0])
                    : (i >= NZD) ? 0.5f * (zw[NZD] - zw[NZD - 1])
                                 : (zT[i] - zT[i - 1]);
        }
        #pragma unroll
        for (int j = 0; j < NL; ++j) {
            const int i = act ? (c0 + j) : 0;
            const float dz = zw[i + 1] - zw[i];
            dzT[j]  = dz;
            DTdz[j] = act ? (DT / dz) : 0.f;
            ezT[j]  = expf(-XI * zT[i]);
            kAf[j]  = (act && (c0 + j) >= 1)       ? (-DT / (dz * dzw_[j]))     : 0.f;
            kCf[j]  = (act && (c0 + j) <= NZD - 2) ? (-DT / (dz * dzw_[j + 1])) : 0.f;
            swN[j]  = act ? (sedc / dzw_[j]) : 0.f;
        }
        swN4 = act ? (sedc / dzw_[NL]) : 0.f;
    }

    // ---- initial state (float4 loads) ----
    float vN[NL], vA[NL], vP[NL], vZ[NL], vD[NL];
    {
        const size_t ib = (size_t)col * NZD + c0;
        if (act) {
            const float4 n4 = *reinterpret_cast<const float4*>(&NO3_0[ib]);
            const float4 a4 = *reinterpret_cast<const float4*>(&NH4_0[ib]);
            const float4 p4 = *reinterpret_cast<const float4*>(&P_0[ib]);
            const float4 z4 = *reinterpret_cast<const float4*>(&Z_0[ib]);
            const float4 d4 = *reinterpret_cast<const float4*>(&D_0[ib]);
            vN[0]=n4.x; vN[1]=n4.y; vN[2]=n4.z; vN[3]=n4.w;
            vA[0]=a4.x; vA[1]=a4.y; vA[2]=a4.z; vA[3]=a4.w;
            vP[0]=p4.x; vP[1]=p4.y; vP[2]=p4.z; vP[3]=p4.w;
            vZ[0]=z4.x; vZ[1]=z4.y; vZ[2]=z4.z; vZ[3]=z4.w;
            vD[0]=d4.x; vD[1]=d4.y; vD[2]=d4.z; vD[3]=d4.w;
        } else {
            #pragma unroll
            for (int j = 0; j < NL; ++j) { vN[j]=vA[j]=vP[j]=vZ[j]=vD[j]=0.f; }
        }
    }

    // frame 0
    const size_t obase = (size_t)col * (NFRAMES * 5 * NZD);
    if (act) {
        *reinterpret_cast<float4*>(&out[obase + 0 * NZD + c0]) = make_float4(vN[0],vN[1],vN[2],vN[3]);
        *reinterpret_cast<float4*>(&out[obase + 1 * NZD + c0]) = make_float4(vA[0],vA[1],vA[2],vA[3]);
        *reinterpret_cast<float4*>(&out[obase + 2 * NZD + c0]) = make_float4(vP[0],vP[1],vP[2],vP[3]);
        *reinterpret_cast<float4*>(&out[obase + 3 * NZD + c0]) = make_float4(vZ[0],vZ[1],vZ[2],vZ[3]);
        *reinterpret_cast<float4*>(&out[obase + 4 * NZD + c0]) = make_float4(vD[0],vD[1],vD[2],vD[3]);
    }

    const float* KzBase = Kz + (size_t)si * (2 * NWN * LWN + 2) * (NZD + 1);
    const float* I0row  = I0 + (size_t)si * (NWN * LWN + 1);

    // ---- factors rebuilt every 4 steps ----
    float t00, t10, t11, t20, t21, t22, t30, t31, t32, t33;   // Dt = T * dd
    float ecf0, ecf1, ecf2;                                   // Ec = ecf . dd
    float aa0, aa1, aa2, cl0, cl1, cl2, cl3;                  // backsub factors
    float E1a, E2a, E1b, E2b, invbF;                          // PCR elimination factors
    float Iez[NL];
    float rap = 0.f;

    // prefetch first Kz row
    float kzc[NL + 1];
    {
        const float* kzp = KzBase + (size_t)(2 * sw0) * (NZD + 1);
        #pragma unroll
        for (int j = 0; j <= NL; ++j) kzc[j] = act ? kzp[c0 + j] : 0.f;
    }

    for (int k = 0; k < NSTEPS; ++k) {
        const int day = k >> 3, hh = k >> 2;

        if ((k & 3) == 0) {
            // ---- tridiagonal coefficients from prefetched Kz ----
            float ac_[NL], cc_[NL];
            #pragma unroll
            for (int j = 0; j < NL; ++j) {
                ac_[j] = kAf[j] * kzc[j];
                cc_[j] = kCf[j] * kzc[j + 1];
            }
            {   // prefetch next Kz row (consumed 4 steps later)
                const float* kzp = KzBase + (size_t)(2 * sw0 + hh + 1) * (NZD + 1);
                #pragma unroll
                for (int j = 0; j <= NL; ++j) kzc[j] = act ? kzp[c0 + j] : 0.f;
            }
            // Thomas LU factors
            const float iv0 = frcp(1.f - ac_[0] - cc_[0]);
            cl0 = cc_[0] * iv0;
            aa0 = ac_[0] * iv0;
            t00 = iv0;
            const float iv1 = frcp(1.f - ac_[1] - cc_[1] - ac_[1] * cl0);
            const float qf1 = ac_[1] * iv1;
            cl1 = cc_[1] * iv1;
            aa1 = -qf1 * aa0;
            t11 = iv1; t10 = -qf1 * t00;
            const float iv2 = frcp(1.f - ac_[2] - cc_[2] - ac_[2] * cl1);
            const float qf2 = ac_[2] * iv2;
            cl2 = cc_[2] * iv2;
            aa2 = -qf2 * aa1;
            t22 = iv2; t21 = -qf2 * t11; t20 = -qf2 * t10;
            const float iv3 = frcp(1.f - ac_[3] - cc_[3] - ac_[3] * cl2);
            const float qf3 = ac_[3] * iv3;
            cl3 = cc_[3] * iv3;
            const float aa3 = -qf3 * aa2;
            t33 = iv3; t32 = -qf3 * t22; t31 = -qf3 * t21; t30 = -qf3 * t20;
            // Ec coefficients
            const float c01 = cl0 * cl1;
            ecf0 = t00 - cl0 * t10 + c01 * t20;
            ecf1 = -cl0 * t11 + c01 * t21;
            ecf2 = c01 * t22;
            // spike + reduced tridiagonal (a,b,c) in block-last cells
            const float F = aa0 - cl0 * (aa1 - cl1 * aa2);
            const float G = cl0 * cl1 * cl2;
            const float Fn = nbr_p1(F);
            const float Gn = nbr_p1(G);
            float aR = aa3;                      // ==0 at lane 0 (ac_[0]==0 chain)
            float bR = 1.f - cl3 * Fn;
            float cR = -cl3 * Gn;                // ==0 at lane ACTL-1 (cl3==0)
            if (!act) { aR = 0.f; bR = 1.f; cR = 0.f; }
            // PCR round 1 (offset 1) — edge reads are 0, killed by zero aR/cR
            const float ib  = frcp(bR);
            const float am  = nbr_m1(aR), ibm = nbr_m1(ib), cm = nbr_m1(cR);
            const float ap  = nbr_p1(aR), ibp = nbr_p1(ib), cp = nbr_p1(cR);
            E1a = -aR * ibm;
            E2a = -cR * ibp;
            const float b1 = bR + E1a * cm + E2a * ap;
            const float a1 = E1a * am;
            const float c1 = E2a * cp;
            // PCR round 2 (offset 2)
            const float ib1  = frcp(b1);
            const float am2  = nbr_m2(a1), ib1m = nbr_m2(ib1), cm2 = nbr_m2(c1);
            const float ap2  = nbr_p2(a1), ib1p = nbr_p2(ib1), cp2 = nbr_p2(c1);
            E1b = -a1 * ib1m;
            E2b = -c1 * ib1p;
            const float b2 = b1 + E1b * cm2 + E2b * ap2;
            invbF = frcp(b2);
        }
        if ((k & 7) == 0) {
            const float I0d = I0row[sw0 + day];
            #pragma unroll
            for (int j = 0; j < NL; ++j) Iez[j] = I0d * ezT[j];
            const float sw = subw[wi * LWN + day + 1];
            rap = 0.05f * (fminf(fmaxf(sw - 30.f, 0.f), 1.f)
                         - fminf(fmaxf(sw - 60.f, 0.f), 1.f));
        }

        // ---- cumsum of P*dzT: local prefix + DPP wave scan ----
        float cl_[NL];
        float run = 0.f;
        #pragma unroll
        for (int j = 0; j < NL; ++j) { run += vP[j] * dzT[j]; cl_[j] = run; }
        const float pref = wave_iscan(run) - run;    // exclusive prefix of lane totals

        // ---- bio tendencies + RHS ----
        float dd[5][NL];
        #pragma unroll
        for (int j = 0; j < NL; ++j) {
            const float csum = pref + cl_[j];
            const float It   = Iez[j] * __expf(-ZETA * csum);
            const float aIt  = pa * It;
            const float Gg   = ETA * aIt * frsq(ETA * ETA + aIt * aIt);
            const float fN   = vN[j] * frcp(KAP + vN[j]);
            const float fA   = vA[j] * frcp(KAP + vA[j]);
            const float eP   = __expf(-PSI * vA[j]);
            const float graz = prho * (1.f - __expf(-LAM * vP[j])) * vZ[j];
            const float bN = MU * vA[j] - Gg * eP * vP[j] * fN;
            const float bA = pvar * vD[j] + pGam * vZ[j] - Gg * vP[j] * fA - MU * vA[j];
            const float bP = Gg * vP[j] * (eP * fN + fA) - graz - pXi * vP[j];
            const float bZ = (1.f - pgam) * graz - pGam * vZ[j];
            const float bD = pgam * graz + pXi * vP[j] - pvar * vD[j];
            dd[0][j] = vN[j] + DT * bN;
            dd[1][j] = vA[j] + DT * bA;
            dd[2][j] = vP[j] + DT * bP;
            dd[3][j] = vZ[j] + DT * bZ;
            dd[4][j] = vD[j] + DT * bD;
        }

        // ---- solve all 5 tracers (independent chains, DPP-only cross-lane) ----
        float X[5][NL];
        #pragma unroll
        for (int t = 0; t < 5; ++t) {
            const float Ec = ecf0 * dd[t][0] + ecf1 * dd[t][1] + ecf2 * dd[t][2];
            const float En = nbr_p1(Ec);
            const float Dt3 = t30 * dd[t][0] + t31 * dd[t][1] + t32 * dd[t][2] + t33 * dd[t][3];
            float dR = Dt3 - cl3 * En;
            dR += E1a * nbr_m1(dR) + E2a * nbr_p1(dR);
            dR += E1b * nbr_m2(dR) + E2b * nbr_p2(dR);
            const float y  = dR * invbF;
            const float xm = nbr_m1(y);          // lane 0: aa*==0 kills xm
            const float Dt0 = t00 * dd[t][0];
            const float Dt1 = t10 * dd[t][0] + t11 * dd[t][1];
            const float Dt2 = t20 * dd[t][0] + t21 * dd[t][1] + t22 * dd[t][2];
            X[t][3] = y;
            X[t][2] = Dt2 - aa2 * xm - cl2 * X[t][3];
            X[t][1] = Dt1 - aa1 * xm - cl1 * X[t][2];
            X[t][0] = Dt0 - aa0 * xm - cl0 * X[t][1];
        }

        // ---- WENO3-Z sediment flux (DPP halos) ----
        float q[NL];
        #pragma unroll
        for (int j = 0; j < NL; ++j) q[j] = X[4][j] * dzT[j];
        const float qm2 = nbr_m1(q[2]);
        const float qm1 = nbr_m1(q[3]);
        const float qn0 = nbr_p1(q[0]);
        const float f0 = (lane == 0) ? 0.f            : weno3z_f(qm2, qm1, q[0]) * swN[0];
        const float f1 = (lane == 0) ? sedc * X[4][0] : weno3z_f(qm1, q[0], q[1]) * swN[1];
        const float f2 = weno3z_f(q[0], q[1], q[2]) * swN[2];
        const float f3 = weno3z_f(q[1], q[2], q[3]) * swN[3];
        const float f4 = (lane == ACTL - 1) ? sedc * X[4][3]
                                            : weno3z_f(q[2], q[3], qn0) * swN4;

        // ---- commit state (+NO3 relaxation) ----
        const float fs[NL + 1] = { f0, f1, f2, f3, f4 };
        #pragma unroll
        for (int j = 0; j < NL; ++j) {
            vD[j] = X[4][j] + (fs[j] - fs[j + 1]) * DTdz[j];
            vN[j] = X[0][j] + (pbet - X[0][j]) * rap;
            vA[j] = X[1][j]; vP[j] = X[2][j]; vZ[j] = X[3][j];
        }

        if (((k + 1) & 7) == 0 && act) {
            const int fr = (k + 1) >> 3;
            const size_t ob = obase + (size_t)fr * (5 * NZD) + c0;
            *reinterpret_cast<float4*>(&out[ob + 0 * NZD]) = make_float4(vN[0],vN[1],vN[2],vN[3]);
            *reinterpret_cast<float4*>(&out[ob + 1 * NZD]) = make_float4(vA[0],vA[1],vA[2],vA[3]);
            *reinterpret_cast<float4*>(&out[ob + 2 * NZD]) = make_float4(vP[0],vP[1],vP[2],vP[3]);
            *reinterpret_cast<float4*>(&out[ob + 3 * NZD]) = make_float4(vZ[0],vZ[1],vZ[2],vZ[3]);
            *reinterpret_cast<float4*>(&out[ob + 4 * NZD]) = make_float4(vD[0],vD[1],vD[2],vD[3]);
        }
    }
}

extern "C" void kernel_launch(void* const* d_in, const int* in_sizes, int n_in,
                              void* d_out, int out_size, void* d_ws, size_t ws_size,
                              hipStream_t stream) {
    const float* Kz    = (const float*)d_in[0];
    const float* I0    = (const float*)d_in[1];
    const float* alpha = (const float*)d_in[2];
    const float* Xi    = (const float*)d_in[3];
    const float* rho   = (const float*)d_in[4];
    const float* gam   = (const float*)d_in[5];
    const float* Gam   = (const float*)d_in[6];
    const float* varp  = (const float*)d_in[7];
    const float* omg   = (const float*)d_in[8];
    const float* bet   = (const float*)d_in[9];
    const float* N0    = (const float*)d_in[10];
    const float* A0    = (const float*)d_in[11];
    const float* P0    = (const float*)d_in[12];
    const float* Z0    = (const float*)d_in[13];
    const float* Dd0   = (const float*)d_in[14];
    const float* sbw   = (const float*)d_in[15];
    const float* zTp   = (const float*)d_in[16];
    const float* zwp   = (const float*)d_in[17];
    float* out = (float*)d_out;

    dim3 grid(NSC * NWN);   // 768 waves, 1 column each
    dim3 block(64);
    hipLaunchKernelGGL(nnpzd_wave, grid, block, 0, stream,
                       Kz, I0, alpha, Xi, rho, gam, Gam, varp, omg, bet,
                       N0, A0, P0, Z0, Dd0, sbw, zTp, zwp, out);
}

// Round 8
// 56.774 us; speedup vs baseline: 2.2641x; 1.0058x over previous
//
#include <hip/hip_runtime.h>

#define NSC 64      // Ns
#define NWN 12      // nw
#define LWN 6       // lw
#define NZD 200     // Nz
#define NFRAMES 6
#define NL 4        // cells per lane
#define ACTL 50     // active lanes (50*4 = 200)

__device__ __forceinline__ float frcp(float x) { return __builtin_amdgcn_rcpf(x); }
__device__ __forceinline__ float frsq(float x) { return __builtin_amdgcn_rsqf(x); }
#if __has_builtin(__builtin_amdgcn_exp2f)
__device__ __forceinline__ float fexp2(float x) { return __builtin_amdgcn_exp2f(x); }
#else
__device__ __forceinline__ float fexp2(float x) { return exp2f(x); }
#endif

// DPP lane-shift moves (bound_ctrl -> 0 at edges).
// wave_shr1 (0x138): lane i reads lane i-1 ; wave_shl1 (0x130): lane i reads lane i+1
template<int CTRL>
__device__ __forceinline__ float dppmov(float x) {
    return __int_as_float(__builtin_amdgcn_update_dpp(0, __float_as_int(x), CTRL, 0xf, 0xf, true));
}
__device__ __forceinline__ float nbr_p1(float x) { return dppmov<0x130>(x); }  // from lane+1
__device__ __forceinline__ float nbr_m1(float x) { return dppmov<0x138>(x); }  // from lane-1
__device__ __forceinline__ float nbr_p2(float x) { return nbr_p1(nbr_p1(x)); }
__device__ __forceinline__ float nbr_m2(float x) { return nbr_m1(nbr_m1(x)); }

template<int CTRL, int RMASK, bool BC>
__device__ __forceinline__ float dppadd(float x) {
    const int t = __builtin_amdgcn_update_dpp(0, __float_as_int(x), CTRL, RMASK, 0xf, BC);
    return x + __int_as_float(t);
}
// wave64 inclusive scan, 6 VALU-DPP ops
__device__ __forceinline__ float wave_iscan(float x) {
    x = dppadd<0x111, 0xf, true>(x);
    x = dppadd<0x112, 0xf, true>(x);
    x = dppadd<0x114, 0xf, true>(x);
    x = dppadd<0x118, 0xf, true>(x);
    x = dppadd<0x142, 0xa, false>(x);
    x = dppadd<0x143, 0xc, false>(x);
    return x;
}

// WENO3-Z with precomputed smoothness b1,b2 and single reciprocal.
// Weights rescaled by 3*(b1+eps)*(b2+eps) > 0 — ratio (hence result) identical.
__device__ __forceinline__ float weno3z_b(float qm, float q0, float qp, float b1, float b2) {
    const float qi1 = 1.5f * q0 - 0.5f * qm;
    const float qi2 = 0.5f * (q0 + qp);
    const float b1e = b1 + 1e-14f;
    const float b2e = b2 + 1e-14f;
    const float tau = fabsf(b2 - b1);
    const float W1 = (b1e + tau) * b2e;
    const float W2 = 2.f * (b2e + tau) * b1e;
    return (W1 * qi1 + W2 * qi2) * frcp(W1 + W2);
}

__global__ __launch_bounds__(64, 1) void nnpzd_wave(
    const float* __restrict__ Kz, const float* __restrict__ I0,
    const float* __restrict__ alpha_p, const float* __restrict__ Xi_p,
    const float* __restrict__ rho_p, const float* __restrict__ gamma_p,
    const float* __restrict__ Gamma_p, const float* __restrict__ varphi_p,
    const float* __restrict__ omega_p, const float* __restrict__ beta_p,
    const float* __restrict__ NO3_0, const float* __restrict__ NH4_0,
    const float* __restrict__ P_0, const float* __restrict__ Z_0,
    const float* __restrict__ D_0, const float* __restrict__ subw,
    const float* __restrict__ zT, const float* __restrict__ zw,
    float* __restrict__ out)
{
    const float XI = 0.067f, ZETA = 0.0095f, LAM = 0.06f, PSI = 1.46f;
    const float MU = 0.25f, ETA = 1.5f, KAP = 1.0f, DT = 0.125f;
    const float LOG2E = 1.44269504088896340736f;
    const float ZL2 = -ZETA * LOG2E;
    const float PL2 = -PSI * LOG2E;
    const float LL2 = -LAM * LOG2E;

    const int col  = blockIdx.x;            // one column per wave
    const int si   = col / NWN;
    const int wi   = col - si * NWN;
    const int lane = threadIdx.x;
    const bool act = lane < ACTL;
    const int  c0  = lane * NL;

    const float pa   = alpha_p[si];
    const float pXi  = Xi_p[si];
    const float prho = rho_p[si];
    const float pgam = gamma_p[si];
    const float pGam = Gamma_p[si];
    const float pvar = varphi_p[si];
    const float sedc = omega_p[si];
    const float pbet = beta_p[si];
    const int   sw0  = (int)subw[wi * LWN];

    // ---- per-lane constant geometry ----
    float dzT[NL], DTdz[NL], ezT[NL], kAf[NL], kCf[NL], swN[NL], swN4;
    {
        float dzw_[NL + 2];
        #pragma unroll
        for (int j = 0; j <= NL + 1; ++j) {
            const int i = act ? (c0 + j) : 0;
            dzw_[j] = (i == 0)   ? 0.5f * (zw[1] - zw[0])
                    : (i >= NZD) ? 0.5f * (zw[NZD] - zw[NZD - 1])
                                 : (zT[i] - zT[i - 1]);
        }
        #pragma unroll
        for (int j = 0; j < NL; ++j) {
            const int i = act ? (c0 + j) : 0;
            const float dz = zw[i + 1] - zw[i];
            dzT[j]  = dz;
            DTdz[j] = act ? (DT / dz) : 0.f;
            ezT[j]  = expf(-XI * zT[i]);
            kAf[j]  = (act && (c0 + j) >= 1)       ? (-DT / (dz * dzw_[j]))     : 0.f;
            kCf[j]  = (act && (c0 + j) <= NZD - 2) ? (-DT / (dz * dzw_[j + 1])) : 0.f;
            swN[j]  = act ? (sedc / dzw_[j]) : 0.f;
        }
        swN4 = act ? (sedc / dzw_[NL]) : 0.f;
    }

    // ---- initial state (float4 loads) ----
    float vN[NL], vA[NL], vP[NL], vZ[NL], vD[NL];
    {
        const size_t ib = (size_t)col * NZD + c0;
        if (act) {
            const float4 n4 = *reinterpret_cast<const float4*>(&NO3_0[ib]);
            const float4 a4 = *reinterpret_cast<const float4*>(&NH4_0[ib]);
            const float4 p4 = *reinterpret_cast<const float4*>(&P_0[ib]);
            const float4 z4 = *reinterpret_cast<const float4*>(&Z_0[ib]);
            const float4 d4 = *reinterpret_cast<const float4*>(&D_0[ib]);
            vN[0]=n4.x; vN[1]=n4.y; vN[2]=n4.z; vN[3]=n4.w;
            vA[0]=a4.x; vA[1]=a4.y; vA[2]=a4.z; vA[3]=a4.w;
            vP[0]=p4.x; vP[1]=p4.y; vP[2]=p4.z; vP[3]=p4.w;
            vZ[0]=z4.x; vZ[1]=z4.y; vZ[2]=z4.z; vZ[3]=z4.w;
            vD[0]=d4.x; vD[1]=d4.y; vD[2]=d4.z; vD[3]=d4.w;
        } else {
            #pragma unroll
            for (int j = 0; j < NL; ++j) { vN[j]=vA[j]=vP[j]=vZ[j]=vD[j]=0.f; }
        }
    }

    // frame 0
    const size_t obase = (size_t)col * (NFRAMES * 5 * NZD);
    if (act) {
        *reinterpret_cast<float4*>(&out[obase + 0 * NZD + c0]) = make_float4(vN[0],vN[1],vN[2],vN[3]);
        *reinterpret_cast<float4*>(&out[obase + 1 * NZD + c0]) = make_float4(vA[0],vA[1],vA[2],vA[3]);
        *reinterpret_cast<float4*>(&out[obase + 2 * NZD + c0]) = make_float4(vP[0],vP[1],vP[2],vP[3]);
        *reinterpret_cast<float4*>(&out[obase + 3 * NZD + c0]) = make_float4(vZ[0],vZ[1],vZ[2],vZ[3]);
        *reinterpret_cast<float4*>(&out[obase + 4 * NZD + c0]) = make_float4(vD[0],vD[1],vD[2],vD[3]);
    }

    const float* KzBase = Kz + (size_t)si * (2 * NWN * LWN + 2) * (NZD + 1);
    const float* I0row  = I0 + (size_t)si * (NWN * LWN + 1);

    // ---- factors rebuilt every 4 steps ----
    float t00, t10, t11, t20, t21, t22, t30, t31, t32, t33;
    float ecf0, ecf1, ecf2;
    float aa0, aa1, aa2, cl0, cl1, cl2, cl3;
    float E1a, E2a, E1b, E2b, invbF;
    float Iez[NL];

    // prefetch first Kz row
    float kzc[NL + 1];
    {
        const float* kzp = KzBase + (size_t)(2 * sw0) * (NZD + 1);
        #pragma unroll
        for (int j = 0; j <= NL; ++j) kzc[j] = act ? kzp[c0 + j] : 0.f;
    }
    // prefetch I0 / subw for day 0
    float curI0 = I0row[sw0];
    float curSw = subw[wi * LWN + 1];
    float nxtI0 = 0.f, nxtSw = 0.f;

    // per-tracer implicit solve (factors captured by reference)
    auto solve = [&](const float* d, float* Xo) {
        const float Ec  = ecf0 * d[0] + ecf1 * d[1] + ecf2 * d[2];
        const float En  = nbr_p1(Ec);
        const float Dt3 = t30 * d[0] + t31 * d[1] + t32 * d[2] + t33 * d[3];
        float dR = Dt3 - cl3 * En;
        dR += E1a * nbr_m1(dR) + E2a * nbr_p1(dR);
        dR += E1b * nbr_m2(dR) + E2b * nbr_p2(dR);
        const float y  = dR * invbF;
        const float xm = nbr_m1(y);
        const float Dt0 = t00 * d[0];
        const float Dt1 = t10 * d[0] + t11 * d[1];
        const float Dt2 = t20 * d[0] + t21 * d[1] + t22 * d[2];
        Xo[3] = y;
        Xo[2] = Dt2 - aa2 * xm - cl2 * Xo[3];
        Xo[1] = Dt1 - aa1 * xm - cl1 * Xo[2];
        Xo[0] = Dt0 - aa0 * xm - cl0 * Xo[1];
    };

    for (int d8 = 0; d8 < 5; ++d8) {
        // prefetch next day's I0/subw (consumed 8 steps later)
        if (d8 < 4) {
            nxtI0 = I0row[sw0 + d8 + 1];
            nxtSw = subw[wi * LWN + d8 + 2];
        }
        #pragma unroll
        for (int j = 0; j < NL; ++j) Iez[j] = curI0 * ezT[j];
        const float rap = 0.05f * (fminf(fmaxf(curSw - 30.f, 0.f), 1.f)
                                 - fminf(fmaxf(curSw - 60.f, 0.f), 1.f));

        for (int k4 = 0; k4 < 2; ++k4) {
            // ---- rebuild matrix factors from prefetched Kz ----
            float ac_[NL], cc_[NL];
            #pragma unroll
            for (int j = 0; j < NL; ++j) {
                ac_[j] = kAf[j] * kzc[j];
                cc_[j] = kCf[j] * kzc[j + 1];
            }
            {   // prefetch next Kz row (row = 2*sw0 + 2*d8 + k4 + 1, always in-bounds)
                const float* kzp = KzBase + (size_t)(2 * sw0 + 2 * d8 + k4 + 1) * (NZD + 1);
                #pragma unroll
                for (int j = 0; j <= NL; ++j) kzc[j] = act ? kzp[c0 + j] : 0.f;
            }
            const float iv0 = frcp(1.f - ac_[0] - cc_[0]);
            cl0 = cc_[0] * iv0;
            aa0 = ac_[0] * iv0;
            t00 = iv0;
            const float iv1 = frcp(1.f - ac_[1] - cc_[1] - ac_[1] * cl0);
            const float qf1 = ac_[1] * iv1;
            cl1 = cc_[1] * iv1;
            aa1 = -qf1 * aa0;
            t11 = iv1; t10 = -qf1 * t00;
            const float iv2 = frcp(1.f - ac_[2] - cc_[2] - ac_[2] * cl1);
            const float qf2 = ac_[2] * iv2;
            cl2 = cc_[2] * iv2;
            aa2 = -qf2 * aa1;
            t22 = iv2; t21 = -qf2 * t11; t20 = -qf2 * t10;
            const float iv3 = frcp(1.f - ac_[3] - cc_[3] - ac_[3] * cl2);
            const float qf3 = ac_[3] * iv3;
            cl3 = cc_[3] * iv3;
            const float aa3 = -qf3 * aa2;
            t33 = iv3; t32 = -qf3 * t22; t31 = -qf3 * t21; t30 = -qf3 * t20;
            const float c01 = cl0 * cl1;
            ecf0 = t00 - cl0 * t10 + c01 * t20;
            ecf1 = -cl0 * t11 + c01 * t21;
            ecf2 = c01 * t22;
            const float F = aa0 - cl0 * (aa1 - cl1 * aa2);
            const float G = cl0 * cl1 * cl2;
            const float Fn = nbr_p1(F);
            const float Gn = nbr_p1(G);
            float aR = aa3;
            float bR = 1.f - cl3 * Fn;
            float cR = -cl3 * Gn;
            if (!act) { aR = 0.f; bR = 1.f; cR = 0.f; }
            const float ib  = frcp(bR);
            const float am  = nbr_m1(aR), ibm = nbr_m1(ib), cm = nbr_m1(cR);
            const float ap  = nbr_p1(aR), ibp = nbr_p1(ib), cp = nbr_p1(cR);
            E1a = -aR * ibm;
            E2a = -cR * ibp;
            const float b1r = bR + E1a * cm + E2a * ap;
            const float a1r = E1a * am;
            const float c1r = E2a * cp;
            const float ib1  = frcp(b1r);
            const float am2  = nbr_m2(a1r), ib1m = nbr_m2(ib1), cm2 = nbr_m2(c1r);
            const float ap2  = nbr_p2(a1r), ib1p = nbr_p2(ib1), cp2 = nbr_p2(c1r);
            E1b = -a1r * ib1m;
            E2b = -c1r * ib1p;
            invbF = frcp(b1r + E1b * cm2 + E2b * ap2);

            #pragma unroll
            for (int k2 = 0; k2 < 4; ++k2) {
                // ---- cumsum of P*dzT ----
                float cl_[NL];
                float run = 0.f;
                #pragma unroll
                for (int j = 0; j < NL; ++j) { run += vP[j] * dzT[j]; cl_[j] = run; }
                const float pref = wave_iscan(run) - run;

                // ---- It-independent tracers first (Z, D) ----
                float grz[NL], ddZ[NL], ddD[NL];
                #pragma unroll
                for (int j = 0; j < NL; ++j) {
                    grz[j] = prho * (1.f - fexp2(LL2 * vP[j])) * vZ[j];
                    ddZ[j] = vZ[j] + DT * ((1.f - pgam) * grz[j] - pGam * vZ[j]);
                    ddD[j] = vD[j] + DT * (pgam * grz[j] + pXi * vP[j] - pvar * vD[j]);
                }
                float XD[NL];
                solve(ddD, XD);        // D first: feeds the long WENO chain

                // ---- It-dependent tracers ----
                float dd0[NL], dd1[NL], dd2[NL];
                #pragma unroll
                for (int j = 0; j < NL; ++j) {
                    const float It  = Iez[j] * fexp2(ZL2 * (pref + cl_[j]));
                    const float aIt = pa * It;
                    const float Gg  = ETA * aIt * frsq(ETA * ETA + aIt * aIt);
                    const float dN  = KAP + vN[j];
                    const float dA  = KAP + vA[j];
                    const float ir  = frcp(dN * dA);
                    const float fN  = vN[j] * dA * ir;
                    const float fA  = vA[j] * dN * ir;
                    const float eP  = fexp2(PL2 * vA[j]);
                    const float GP  = Gg * vP[j];
                    const float bN = MU * vA[j] - GP * eP * fN;
                    const float bA = pvar * vD[j] + pGam * vZ[j] - GP * fA - MU * vA[j];
                    const float bP = GP * (eP * fN + fA) - grz[j] - pXi * vP[j];
                    dd0[j] = vN[j] + DT * bN;
                    dd1[j] = vA[j] + DT * bA;
                    dd2[j] = vP[j] + DT * bP;
                }

                // ---- WENO3-Z sediment flux on XD (shared smoothness indicators) ----
                float q[NL];
                #pragma unroll
                for (int j = 0; j < NL; ++j) q[j] = XD[j] * dzT[j];
                const float qm1 = nbr_m1(q[3]);
                const float qm2 = nbr_m1(q[2]);
                const float dq0 = q[0] - qm1;
                const float dq1 = q[1] - q[0];
                const float dq2 = q[2] - q[1];
                const float dq3 = q[3] - q[2];
                const float s0 = dq0 * dq0, s1 = dq1 * dq1, s2 = dq2 * dq2, s3 = dq3 * dq3;
                const float s4 = nbr_p1(s0);
                const float sm = nbr_m1(s3);
                const float qn0 = q[3] + nbr_p1(dq0);   // q[0] of lane+1
                const float f0 = (lane == 0) ? 0.f           : weno3z_b(qm2, qm1, q[0], sm, s0) * swN[0];
                const float f1 = (lane == 0) ? sedc * XD[0]  : weno3z_b(qm1, q[0], q[1], s0, s1) * swN[1];
                const float f2 = weno3z_b(q[0], q[1], q[2], s1, s2) * swN[2];
                const float f3 = weno3z_b(q[1], q[2], q[3], s2, s3) * swN[3];
                const float f4 = (lane == ACTL - 1) ? sedc * XD[3]
                                                    : weno3z_b(q[2], q[3], qn0, s3, s4) * swN4;
                const float fs[NL + 1] = { f0, f1, f2, f3, f4 };
                #pragma unroll
                for (int j = 0; j < NL; ++j)
                    vD[j] = XD[j] + (fs[j] - fs[j + 1]) * DTdz[j];

                // ---- remaining solves + commit ----
                float XZ[NL], X0[NL], X1[NL], X2[NL];
                solve(ddZ, XZ);
                solve(dd0, X0);
                solve(dd1, X1);
                solve(dd2, X2);
                #pragma unroll
                for (int j = 0; j < NL; ++j) {
                    vZ[j] = XZ[j];
                    vN[j] = X0[j] + (pbet - X0[j]) * rap;
                    vA[j] = X1[j];
                    vP[j] = X2[j];
                }

                if (k4 == 1 && k2 == 3 && act) {     // end of day: frame d8+1
                    const size_t ob = obase + (size_t)(d8 + 1) * (5 * NZD) + c0;
                    *reinterpret_cast<float4*>(&out[ob + 0 * NZD]) = make_float4(vN[0],vN[1],vN[2],vN[3]);
                    *reinterpret_cast<float4*>(&out[ob + 1 * NZD]) = make_float4(vA[0],vA[1],vA[2],vA[3]);
                    *reinterpret_cast<float4*>(&out[ob + 2 * NZD]) = make_float4(vP[0],vP[1],vP[2],vP[3]);
                    *reinterpret_cast<float4*>(&out[ob + 3 * NZD]) = make_float4(vZ[0],vZ[1],vZ[2],vZ[3]);
                    *reinterpret_cast<float4*>(&out[ob + 4 * NZD]) = make_float4(vD[0],vD[1],vD[2],vD[3]);
                }
            }
        }
        if (d8 < 4) { curI0 = nxtI0; curSw = nxtSw; }
    }
}

extern "C" void kernel_launch(void* const* d_in, const int* in_sizes, int n_in,
                              void* d_out, int out_size, void* d_ws, size_t ws_size,
                              hipStream_t stream) {
    const float* Kz    = (const float*)d_in[0];
    const float* I0    = (const float*)d_in[1];
    const float* alpha = (const float*)d_in[2];
    const float* Xi    = (const float*)d_in[3];
    const float* rho   = (const float*)d_in[4];
    const float* gam   = (const float*)d_in[5];
    const float* Gam   = (const float*)d_in[6];
    const float* varp  = (const float*)d_in[7];
    const float* omg   = (const float*)d_in[8];
    const float* bet   = (const float*)d_in[9];
    const float* N0    = (const float*)d_in[10];
    const float* A0    = (const float*)d_in[11];
    const float* P0    = (const float*)d_in[12];
    const float* Z0    = (const float*)d_in[13];
    const float* Dd0   = (const float*)d_in[14];
    const float* sbw   = (const float*)d_in[15];
    const float* zTp   = (const float*)d_in[16];
    const float* zwp   = (const float*)d_in[17];
    float* out = (float*)d_out;

    dim3 grid(NSC * NWN);   // 768 waves, 1 column each
    dim3 block(64);
    hipLaunchKernelGGL(nnpzd_wave, grid, block, 0, stream,
                       Kz, I0, alpha, Xi, rho, gam, Gam, varp, omg, bet,
                       N0, A0, P0, Z0, Dd0, sbw, zTp, zwp, out);
}